// Round 4
// baseline (15753.271 us; speedup 1.0000x reference)
//
#include <hip/hip_runtime.h>
#include <math.h>

#define DMEM   1024
#define NGATES 2048
#define NB     128
#define NT     32

__device__ inline float sigm(float x) { return 1.f / (1.f + __expf(-x)); }

// ---------------------------------------------------------------------------
// gemm_d: fp32 GEMM, double-buffered LDS, 128xBN tile (BN=128 or 64),
// 256 threads, 8x(BN/16) per thread -> 2 (or 1.33) FLOP per LDS byte.
//  A (M x K) row-major; W (K x N) row-major; C (M x N).
//  AMODE 0: plain A.  AMODE 1: A = relu(P0 + P1 + abias[k]) (partial-sum fuse)
//  SPLITK: blockIdx.z % SPLITK = k-chunk (C += kc*psC);
//          blockIdx.z / SPLITK = batch slot (A += slot*zsA etc.)
//  BIAS: add bias[col] at store (only for SPLITK==1 uses).
// ---------------------------------------------------------------------------
template<int BN, int AMODE, int SPLITK, bool BIAS>
__global__ __launch_bounds__(256)
void gemm_d(const float* __restrict__ A, int lda, long zsA, long psA,
            const float* __restrict__ abias,
            const float* __restrict__ W, int ldw, long zsW,
            const float* __restrict__ bias,
            float* __restrict__ C, int ldc, long zsC, long psC,
            int K)
{
    __shared__ float As[2][32][132];
    __shared__ float Bs[2][32][BN + 4];

    const int tid  = threadIdx.x;
    const int slot = blockIdx.z / SPLITK;
    const int kc   = blockIdx.z % SPLITK;
    A += (long)slot * zsA;
    W += (long)slot * zsW;
    C += (long)slot * zsC + (long)kc * psC;
    const int kchunk = K / SPLITK;
    const int kbeg   = kc * kchunk;
    const int NIT    = kchunk / 32;

    const int row0 = blockIdx.y * 128;
    const int col0 = blockIdx.x * BN;

    // staging indices: A tile 128x32 (16 floats/thr), B tile 32xBN
    const int arow = tid >> 1;              // 0..127
    const int ah   = (tid & 1) * 16;        // 0 / 16
    const int bkr  = tid >> 3;              // 0..31
    const int bc   = (tid & 7) * (BN / 8);  // BN=128: *16 ; BN=64: *8
    // compute indices
    const int tr = (tid >> 4) << 2;         // 0..60
    const int tc = (tid & 15) << 2;         // 0..60

    float4 a_st[4];
    float4 b_st[BN / 32];

    auto load_regs = [&](int k0) {
        const float* ap = A + (long)(row0 + arow) * lda + k0 + ah;
#pragma unroll
        for (int j = 0; j < 4; ++j) {
            if (AMODE == 0) {
                a_st[j] = *(const float4*)(ap + j * 4);
            } else {
                float4 p0 = *(const float4*)(ap + j * 4);
                float4 p1 = *(const float4*)(ap + psA + j * 4);
                float4 bb = *(const float4*)(abias + k0 + ah + j * 4);
                a_st[j].x = fmaxf(p0.x + p1.x + bb.x, 0.f);
                a_st[j].y = fmaxf(p0.y + p1.y + bb.y, 0.f);
                a_st[j].z = fmaxf(p0.z + p1.z + bb.z, 0.f);
                a_st[j].w = fmaxf(p0.w + p1.w + bb.w, 0.f);
            }
        }
        const float* wp = W + (long)(k0 + bkr) * ldw + col0 + bc;
#pragma unroll
        for (int j = 0; j < BN / 32; ++j)
            b_st[j] = *(const float4*)(wp + j * 4);
    };

    auto write_lds = [&](int p) {
#pragma unroll
        for (int j = 0; j < 4; ++j) {
            As[p][ah + j * 4 + 0][arow] = a_st[j].x;
            As[p][ah + j * 4 + 1][arow] = a_st[j].y;
            As[p][ah + j * 4 + 2][arow] = a_st[j].z;
            As[p][ah + j * 4 + 3][arow] = a_st[j].w;
        }
#pragma unroll
        for (int j = 0; j < BN / 32; ++j)
            *(float4*)&Bs[p][bkr][bc + j * 4] = b_st[j];
    };

    float acc[8][BN / 16] = {};

    auto compute = [&](int p) {
#pragma unroll
        for (int kk = 0; kk < 32; ++kk) {
            float a[8], b[BN / 16];
            *(float4*)&a[0] = *(const float4*)&As[p][kk][tr];
            *(float4*)&a[4] = *(const float4*)&As[p][kk][64 + tr];
            *(float4*)&b[0] = *(const float4*)&Bs[p][kk][tc];
            if (BN == 128)
                *(float4*)&b[4] = *(const float4*)&Bs[p][kk][64 + tc];
#pragma unroll
            for (int i = 0; i < 8; ++i)
#pragma unroll
                for (int j = 0; j < BN / 16; ++j)
                    acc[i][j] = fmaf(a[i], b[j], acc[i][j]);
        }
    };

    load_regs(kbeg);
    write_lds(0);
    int p = 0;
    for (int it = 0; it < NIT; ++it) {
        __syncthreads();
        if (it + 1 < NIT) load_regs(kbeg + (it + 1) * 32);
        compute(p);
        if (it + 1 < NIT) write_lds(p ^ 1);
        p ^= 1;
    }

    // epilogue
#pragma unroll
    for (int jh = 0; jh < BN / 64; ++jh) {
        int cbase = col0 + jh * 64 + tc;
        float4 bv = make_float4(0.f, 0.f, 0.f, 0.f);
        if (BIAS) bv = *(const float4*)&bias[cbase];
#pragma unroll
        for (int ih = 0; ih < 2; ++ih) {
#pragma unroll
            for (int i = 0; i < 4; ++i) {
                int row = row0 + ih * 64 + tr + i;
                float4 o = make_float4(acc[ih * 4 + i][jh * 4 + 0] + bv.x,
                                       acc[ih * 4 + i][jh * 4 + 1] + bv.y,
                                       acc[ih * 4 + i][jh * 4 + 2] + bv.z,
                                       acc[ih * 4 + i][jh * 4 + 3] + bv.w);
                *(float4*)(C + (long)row * ldc + cbase) = o;
            }
        }
    }
}

// ---------------------------------------------------------------------------
// block reduction (256 threads) of (sum, sumsq); safe for repeated use
// ---------------------------------------------------------------------------
__device__ inline void block_reduce2(float& s1, float& s2)
{
    __shared__ float red[2][4];
    __syncthreads();
#pragma unroll
    for (int off = 32; off > 0; off >>= 1) {
        s1 += __shfl_down(s1, off, 64);
        s2 += __shfl_down(s2, off, 64);
    }
    int tid = threadIdx.x;
    if ((tid & 63) == 0) { red[0][tid >> 6] = s1; red[1][tid >> 6] = s2; }
    __syncthreads();
    s1 = red[0][0] + red[0][1] + red[0][2] + red[0][3];
    s2 = red[1][0] + red[1][1] + red[1][2] + red[1][3];
}

// ---------------------------------------------------------------------------
// ln1 (t=0): m1 = LN(mem0 + v[:,0])*g+b ; tm = tanh(mem0)
// ---------------------------------------------------------------------------
__global__ __launch_bounds__(256)
void ln1_kern(const float* __restrict__ memprev, const float* __restrict__ v,
              const float* __restrict__ g, const float* __restrict__ bb,
              float* __restrict__ m1, float* __restrict__ tm)
{
    const int row = blockIdx.x;
    const int b   = row >> 3;
    const int d   = threadIdx.x << 2;

    float4 mv = *(const float4*)(memprev + (long)row * DMEM + d);
    float4 vv = *(const float4*)(v + ((long)b * NT) * DMEM + d);

    *(float4*)(tm + (long)row * DMEM + d) =
        make_float4(tanhf(mv.x), tanhf(mv.y), tanhf(mv.z), tanhf(mv.w));

    float x0 = mv.x + vv.x, x1 = mv.y + vv.y, x2 = mv.z + vv.z, x3 = mv.w + vv.w;
    float s1 = x0 + x1 + x2 + x3;
    float s2 = x0 * x0 + x1 * x1 + x2 * x2 + x3 * x3;
    block_reduce2(s1, s2);
    float mean = s1 * (1.f / 1024.f);
    float var  = s2 * (1.f / 1024.f) - mean * mean;
    float inv  = 1.f / sqrtf(var + 1e-5f);

    float4 gg = *(const float4*)&g[d];
    float4 bv = *(const float4*)&bb[d];
    *(float4*)(m1 + (long)row * DMEM + d) =
        make_float4((x0 - mean) * inv * gg.x + bv.x,
                    (x1 - mean) * inv * gg.y + bv.y,
                    (x2 - mean) * inv * gg.z + bv.z,
                    (x3 - mean) * inv * gg.w + bv.w);
}

// ---------------------------------------------------------------------------
// fused per-step tail: h2=relu(h2P0+h2P1+bm); t2=tanh(LN2(m1+h2));
// out = sig(gm+gi+ib)*t2 + sig(gm'+gi'+fb)*mem;
// if !last: tm=tanh(out); m1'=LN1(out+v[:,t+1])
// ---------------------------------------------------------------------------
__global__ __launch_bounds__(256)
void step_fused(const float* __restrict__ m1in, const float* __restrict__ h2P,
                const float* __restrict__ bm,
                const float* __restrict__ g2, const float* __restrict__ b2,
                const float* __restrict__ gmP, const float* __restrict__ gi, int t,
                const float* __restrict__ memprev,
                const float* __restrict__ fbp, const float* __restrict__ ibp,
                const float* __restrict__ v,
                const float* __restrict__ g1, const float* __restrict__ b1,
                float* __restrict__ outp, float* __restrict__ m1out,
                float* __restrict__ tm, int last)
{
    const int row = blockIdx.x;          // b*8+s
    const int b   = row >> 3;
    const int d   = threadIdx.x << 2;
    const long o  = (long)row * DMEM + d;

    // ---- ln2 ----
    float4 a  = *(const float4*)(m1in + o);
    float4 q0 = *(const float4*)(h2P + o);
    float4 q1 = *(const float4*)(h2P + 1048576 + o);
    float4 bb = *(const float4*)&bm[d];
    float x0 = a.x + fmaxf(q0.x + q1.x + bb.x, 0.f);
    float x1 = a.y + fmaxf(q0.y + q1.y + bb.y, 0.f);
    float x2 = a.z + fmaxf(q0.z + q1.z + bb.z, 0.f);
    float x3 = a.w + fmaxf(q0.w + q1.w + bb.w, 0.f);

    float s1 = x0 + x1 + x2 + x3;
    float s2 = x0 * x0 + x1 * x1 + x2 * x2 + x3 * x3;
    block_reduce2(s1, s2);
    float mean = s1 * (1.f / 1024.f);
    float var  = s2 * (1.f / 1024.f) - mean * mean;
    float inv  = 1.f / sqrtf(var + 1e-5f);

    float4 gg = *(const float4*)&g2[d];
    float4 b2v = *(const float4*)&b2[d];
    float t20 = tanhf((x0 - mean) * inv * gg.x + b2v.x);
    float t21 = tanhf((x1 - mean) * inv * gg.y + b2v.y);
    float t22 = tanhf((x2 - mean) * inv * gg.z + b2v.z);
    float t23 = tanhf((x3 - mean) * inv * gg.w + b2v.w);

    // ---- gates ----
    const float ib = *ibp, fb = *fbp;
    const long go = (long)row * NGATES + d;
    float4 ga0 = *(const float4*)(gmP + go);
    float4 ga1 = *(const float4*)(gmP + 2097152 + go);
    float4 gb0 = *(const float4*)(gmP + go + DMEM);
    float4 gb1 = *(const float4*)(gmP + 2097152 + go + DMEM);
    const long io = ((long)b * NT + t) * NGATES + d;
    float4 i0 = *(const float4*)(gi + io);
    float4 i1 = *(const float4*)(gi + io + DMEM);
    float4 mv = *(const float4*)(memprev + o);

    float4 out;
    out.x = sigm(ga0.x + ga1.x + i0.x + ib) * t20 + sigm(gb0.x + gb1.x + i1.x + fb) * mv.x;
    out.y = sigm(ga0.y + ga1.y + i0.y + ib) * t21 + sigm(gb0.y + gb1.y + i1.y + fb) * mv.y;
    out.z = sigm(ga0.z + ga1.z + i0.z + ib) * t22 + sigm(gb0.z + gb1.z + i1.z + fb) * mv.z;
    out.w = sigm(ga0.w + ga1.w + i0.w + ib) * t23 + sigm(gb0.w + gb1.w + i1.w + fb) * mv.w;
    *(float4*)(outp + o) = out;

    // ---- next-step ln1 ----
    if (!last) {
        float4 vv = *(const float4*)(v + ((long)b * NT + t + 1) * DMEM + d);
        *(float4*)(tm + o) =
            make_float4(tanhf(out.x), tanhf(out.y), tanhf(out.z), tanhf(out.w));

        float y0 = out.x + vv.x, y1 = out.y + vv.y;
        float y2 = out.z + vv.z, y3 = out.w + vv.w;
        float u1 = y0 + y1 + y2 + y3;
        float u2 = y0 * y0 + y1 * y1 + y2 * y2 + y3 * y3;
        block_reduce2(u1, u2);
        float mean1 = u1 * (1.f / 1024.f);
        float var1  = u2 * (1.f / 1024.f) - mean1 * mean1;
        float inv1  = 1.f / sqrtf(var1 + 1e-5f);

        float4 g1v = *(const float4*)&g1[d];
        float4 b1v = *(const float4*)&b1[d];
        *(float4*)(m1out + o) =
            make_float4((y0 - mean1) * inv1 * g1v.x + b1v.x,
                        (y1 - mean1) * inv1 * g1v.y + b1v.y,
                        (y2 - mean1) * inv1 * g1v.z + b1v.z,
                        (y3 - mean1) * inv1 * g1v.w + b1v.w);
    }
}

// ---------------------------------------------------------------------------
// ga (in-place): inp = relu(rep_w * inp)
// ---------------------------------------------------------------------------
__global__ __launch_bounds__(256)
void ga_kern(float* __restrict__ inp, const float* __restrict__ rep)
{
    long i4 = ((long)blockIdx.x * 256 + threadIdx.x) << 2;
    float4 x = *(const float4*)&inp[i4];
    float4 r = *(const float4*)&rep[i4 & (DMEM - 1)];
    *(float4*)&inp[i4] = make_float4(fmaxf(r.x * x.x, 0.f), fmaxf(r.y * x.y, 0.f),
                                     fmaxf(r.z * x.z, 0.f), fmaxf(r.w * x.w, 0.f));
}

// ---------------------------------------------------------------------------
extern "C" void kernel_launch(void* const* d_in, const int* in_sizes, int n_in,
                              void* d_out, int out_size, void* d_ws, size_t ws_size,
                              hipStream_t stream)
{
    const float* x    = (const float*)d_in[0];
    const float* mem0 = (const float*)d_in[1];
    const float* Wi   = (const float*)d_in[2];
    const float* bi   = (const float*)d_in[3];
    // d_in[4..7] = Wq,bq,Wk,bk : dead (softmax over singleton axis == 1)
    const float* Wv   = (const float*)d_in[8];
    const float* bv   = (const float*)d_in[9];
    const float* Wm   = (const float*)d_in[10];
    const float* bm   = (const float*)d_in[11];
    const float* ln1g = (const float*)d_in[12];
    const float* ln1b = (const float*)d_in[13];
    const float* ln2g = (const float*)d_in[14];
    const float* ln2b = (const float*)d_in[15];
    const float* repw = (const float*)d_in[16];
    const float* Wg   = (const float*)d_in[17];
    const float* bg   = (const float*)d_in[18];
    const float* Wmg  = (const float*)d_in[19];
    const float* fbp  = (const float*)d_in[20];
    const float* ibp  = (const float*)d_in[21];

    float* out = (float*)d_out;
    char*  ws  = (char*)d_ws;
    const long MB = 1024L * 1024L;

    // persistent across scan
    float* v    = (float*)(ws + 0 * MB);   // 16 MB [4096][1024]
    float* gi   = (float*)(ws + 16 * MB);  // 32 MB [4096][2048]
    // per-step
    float* m1   = (float*)(ws + 48 * MB);  //  4 MB
    float* tm   = (float*)(ws + 52 * MB);  //  4 MB
    float* gmP  = (float*)(ws + 56 * MB);  // 16 MB [2][1024][2048]
    float* hP   = (float*)(ws + 56 * MB);  //  8 MB [2][1024][1024] (dead before gm)
    float* h2P  = (float*)(ws + 72 * MB);  //  8 MB [2][1024][1024]
    // phase-A transient (dead before ln1/step usage of 48..64)
    float* inp  = (float*)(ws + 48 * MB);  // 16 MB [4096][1024]
    // peak exactly 80 MB

    dim3 blk(256);

    // ---- phase A ----
    // inp = x @ Wi + bi
    gemm_d<128, 0, 1, true><<<dim3(8, 32, 1), blk, 0, stream>>>(
        x, 1024, 0, 0, nullptr, Wi, 1024, 0, bi, inp, 1024, 0, 0, 1024);
    // v = inp @ Wv + bv
    gemm_d<128, 0, 1, true><<<dim3(8, 32, 1), blk, 0, stream>>>(
        inp, 1024, 0, 0, nullptr, Wv, 1024, 0, bv, v, 1024, 0, 0, 1024);
    // inp <- relu(rep_w * inp)
    ga_kern<<<4096, blk, 0, stream>>>(inp, repw);
    // gi = ga @ Wg + bg
    gemm_d<128, 0, 1, true><<<dim3(16, 32, 1), blk, 0, stream>>>(
        inp, 1024, 0, 0, nullptr, Wg, 2048, 0, bg, gi, 2048, 0, 0, 1024);

    // ---- t=0 LN1 + tanh(mem0) ----
    ln1_kern<<<1024, blk, 0, stream>>>(mem0, v, ln1g, ln1b, m1, tm);

    // ---- recurrent scan; state lives in d_out (outs[t] == new_mem_t) ----
    const long stepN = (long)NB * 8 * DMEM;   // 1,048,576 floats
    for (int t = 0; t < NT; ++t) {
        const float* memprev = (t == 0) ? mem0 : out + (long)(t - 1) * stepN;

        // hP = m1 @ Wm  (split-K2, 128x64 tiles, 256 blocks)
        gemm_d<64, 0, 2, false><<<dim3(16, 8, 2), blk, 0, stream>>>(
            m1, 1024, 0, 0, nullptr, Wm, 1024, 0, nullptr,
            hP, 1024, 0, 1048576, 1024);
        // h2P = relu(hP0+hP1+bm) @ Wm  (split-K2, staging-fused relu)
        gemm_d<64, 1, 2, false><<<dim3(16, 8, 2), blk, 0, stream>>>(
            hP, 1024, 0, 1048576, bm, Wm, 1024, 0, nullptr,
            h2P, 1024, 0, 1048576, 1024);
        // gmP = tm @ Wmg  (batched slots, split-K2, 128x128 tiles, 256 blocks)
        gemm_d<128, 0, 2, false><<<dim3(16, 1, 16), blk, 0, stream>>>(
            tm, 8192, 1024, 0, nullptr, Wmg, 2048, 2097152, nullptr,
            gmP, 16384, 2048, 2097152, 1024);
        // fused: ln2 + gates + state update + next ln1
        step_fused<<<1024, blk, 0, stream>>>(
            m1, h2P, bm, ln2g, ln2b, gmP, gi, t, memprev, fbp, ibp,
            v, ln1g, ln1b, out + (long)t * stepN, m1, tm,
            (t == NT - 1) ? 1 : 0);
    }

    // final_mem = outs[31]
    hipMemcpyAsync(out + 32L * stepN, out + 31L * stepN, stepN * sizeof(float),
                   hipMemcpyDeviceToDevice, stream);
}

// Round 5
// 5278.655 us; speedup vs baseline: 2.9843x; 2.9843x over previous
//
#include <hip/hip_runtime.h>
#include <math.h>

#define DMEM   1024
#define NGATES 2048
#define NB     128
#define NT     32

__device__ inline float sigm(float x) { return 1.f / (1.f + __expf(-x)); }

// ---------------------------------------------------------------------------
// gemm128: fp32, C = A@W + bias. 128x128 tile, BK=16, 256 thr, 8x8/thread.
// Single LDS buffer, prefetch permutation (load it+1 before compute it).
// AMODE 0: plain A. AMODE 2: A = relu(rep[k] * A[m][k]) (ga-fusion for gi).
// ---------------------------------------------------------------------------
template<int AMODE>
__global__ __launch_bounds__(256)
void gemm128(const float* __restrict__ A, int lda,
             const float* __restrict__ rep,
             const float* __restrict__ W, int N,
             const float* __restrict__ bias,
             float* __restrict__ C, int K)
{
    __shared__ float As[16][132];
    __shared__ float Bs[16][132];
    const int tid  = threadIdx.x;
    const int tr   = (tid >> 4) << 2;          // 0..60
    const int tc   = (tid & 15) << 2;          // 0..60
    const int row0 = blockIdx.y * 128, col0 = blockIdx.x * 128;
    const int arow = tid >> 1, ah = (tid & 1) * 8;
    const int brow = tid >> 4, bcol = (tid & 15) * 8;

    float4 a0, a1, b0, b1;
    auto LOAD = [&](int k0) {
        const float* ap = A + (long)(row0 + arow) * lda + k0 + ah;
        a0 = *(const float4*)ap;
        a1 = *(const float4*)(ap + 4);
        if (AMODE == 2) {
            float4 r0 = *(const float4*)(rep + k0 + ah);
            float4 r1 = *(const float4*)(rep + k0 + ah + 4);
            a0.x = fmaxf(a0.x * r0.x, 0.f); a0.y = fmaxf(a0.y * r0.y, 0.f);
            a0.z = fmaxf(a0.z * r0.z, 0.f); a0.w = fmaxf(a0.w * r0.w, 0.f);
            a1.x = fmaxf(a1.x * r1.x, 0.f); a1.y = fmaxf(a1.y * r1.y, 0.f);
            a1.z = fmaxf(a1.z * r1.z, 0.f); a1.w = fmaxf(a1.w * r1.w, 0.f);
        }
        const float* bp = W + (long)(k0 + brow) * N + col0 + bcol;
        b0 = *(const float4*)bp;
        b1 = *(const float4*)(bp + 4);
    };

    float acc[8][8] = {};
    LOAD(0);
    const int NIT = K >> 4;
    for (int it = 0; it < NIT; ++it) {
        __syncthreads();
        As[ah + 0][arow] = a0.x; As[ah + 1][arow] = a0.y;
        As[ah + 2][arow] = a0.z; As[ah + 3][arow] = a0.w;
        As[ah + 4][arow] = a1.x; As[ah + 5][arow] = a1.y;
        As[ah + 6][arow] = a1.z; As[ah + 7][arow] = a1.w;
        *(float4*)&Bs[brow][bcol]     = b0;
        *(float4*)&Bs[brow][bcol + 4] = b1;
        __syncthreads();
        if (it + 1 < NIT) LOAD((it + 1) << 4);
#pragma unroll
        for (int kk = 0; kk < 16; ++kk) {
            float a[8], b[8];
            *(float4*)&a[0] = *(const float4*)&As[kk][tr];
            *(float4*)&a[4] = *(const float4*)&As[kk][64 + tr];
            *(float4*)&b[0] = *(const float4*)&Bs[kk][tc];
            *(float4*)&b[4] = *(const float4*)&Bs[kk][64 + tc];
#pragma unroll
            for (int i = 0; i < 8; ++i)
#pragma unroll
                for (int j = 0; j < 8; ++j)
                    acc[i][j] = fmaf(a[i], b[j], acc[i][j]);
        }
    }

#pragma unroll
    for (int jh = 0; jh < 2; ++jh) {
        int cbase = col0 + jh * 64 + tc;
        float4 bv = *(const float4*)&bias[cbase];
#pragma unroll
        for (int ih = 0; ih < 2; ++ih) {
#pragma unroll
            for (int i = 0; i < 4; ++i) {
                int row = row0 + ih * 64 + tr + i;
                *(float4*)(C + (long)row * N + cbase) =
                    make_float4(acc[ih * 4 + i][jh * 4 + 0] + bv.x,
                                acc[ih * 4 + i][jh * 4 + 1] + bv.y,
                                acc[ih * 4 + i][jh * 4 + 2] + bv.z,
                                acc[ih * 4 + i][jh * 4 + 3] + bv.w);
            }
        }
    }
}

// ---------------------------------------------------------------------------
// gemm64_core: 64x64 tile, BK=32, 4x4/thread, single LDS buffer + prefetch.
// AMODE 0: plain A.  AMODE 1: A = relu(P0 + P1 + abias[k]) (fold h1 partials)
// ---------------------------------------------------------------------------
template<int AMODE>
__device__ __forceinline__ void gemm64_core(
    const float* __restrict__ A, int lda, long psA,
    const float* __restrict__ abias,
    const float* __restrict__ W, int ldw,
    float* __restrict__ C, int ldc,
    int row0, int col0, int kbeg, int kend,
    float (*As)[68], float (*Bs)[68])
{
    const int tid  = threadIdx.x;
    const int tr   = (tid >> 4) << 2, tc = (tid & 15) << 2;
    const int arow = tid >> 2, aseg = (tid & 3) * 8;
    const int brow = tid >> 3, bcol = (tid & 7) * 8;

    float4 a0, a1, b0, b1;
    auto LOAD = [&](int k0) {
        const float* ap = A + (long)(row0 + arow) * lda + k0 + aseg;
        if (AMODE == 0) {
            a0 = *(const float4*)ap;
            a1 = *(const float4*)(ap + 4);
        } else {
            float4 p0 = *(const float4*)ap;
            float4 p1 = *(const float4*)(ap + psA);
            float4 q0 = *(const float4*)(ap + 4);
            float4 q1 = *(const float4*)(ap + psA + 4);
            float4 c0 = *(const float4*)(abias + k0 + aseg);
            float4 c1 = *(const float4*)(abias + k0 + aseg + 4);
            a0.x = fmaxf(p0.x + p1.x + c0.x, 0.f);
            a0.y = fmaxf(p0.y + p1.y + c0.y, 0.f);
            a0.z = fmaxf(p0.z + p1.z + c0.z, 0.f);
            a0.w = fmaxf(p0.w + p1.w + c0.w, 0.f);
            a1.x = fmaxf(q0.x + q1.x + c1.x, 0.f);
            a1.y = fmaxf(q0.y + q1.y + c1.y, 0.f);
            a1.z = fmaxf(q0.z + q1.z + c1.z, 0.f);
            a1.w = fmaxf(q0.w + q1.w + c1.w, 0.f);
        }
        const float* bp = W + (long)(k0 + brow) * ldw + col0 + bcol;
        b0 = *(const float4*)bp;
        b1 = *(const float4*)(bp + 4);
    };

    float acc[4][4] = {};
    LOAD(kbeg);
    const int NIT = (kend - kbeg) >> 5;
    for (int it = 0; it < NIT; ++it) {
        __syncthreads();
        As[aseg + 0][arow] = a0.x; As[aseg + 1][arow] = a0.y;
        As[aseg + 2][arow] = a0.z; As[aseg + 3][arow] = a0.w;
        As[aseg + 4][arow] = a1.x; As[aseg + 5][arow] = a1.y;
        As[aseg + 6][arow] = a1.z; As[aseg + 7][arow] = a1.w;
        *(float4*)&Bs[brow][bcol]     = b0;
        *(float4*)&Bs[brow][bcol + 4] = b1;
        __syncthreads();
        if (it + 1 < NIT) LOAD(kbeg + ((it + 1) << 5));
#pragma unroll
        for (int kk = 0; kk < 32; ++kk) {
            float4 av = *(const float4*)&As[kk][tr];
            float4 bv = *(const float4*)&Bs[kk][tc];
            acc[0][0] = fmaf(av.x, bv.x, acc[0][0]); acc[0][1] = fmaf(av.x, bv.y, acc[0][1]);
            acc[0][2] = fmaf(av.x, bv.z, acc[0][2]); acc[0][3] = fmaf(av.x, bv.w, acc[0][3]);
            acc[1][0] = fmaf(av.y, bv.x, acc[1][0]); acc[1][1] = fmaf(av.y, bv.y, acc[1][1]);
            acc[1][2] = fmaf(av.y, bv.z, acc[1][2]); acc[1][3] = fmaf(av.y, bv.w, acc[1][3]);
            acc[2][0] = fmaf(av.z, bv.x, acc[2][0]); acc[2][1] = fmaf(av.z, bv.y, acc[2][1]);
            acc[2][2] = fmaf(av.z, bv.z, acc[2][2]); acc[2][3] = fmaf(av.z, bv.w, acc[2][3]);
            acc[3][0] = fmaf(av.w, bv.x, acc[3][0]); acc[3][1] = fmaf(av.w, bv.y, acc[3][1]);
            acc[3][2] = fmaf(av.w, bv.z, acc[3][2]); acc[3][3] = fmaf(av.w, bv.w, acc[3][3]);
        }
    }

#pragma unroll
    for (int i = 0; i < 4; ++i)
        *(float4*)(C + (long)(row0 + tr + i) * ldc + col0 + tc) =
            make_float4(acc[i][0], acc[i][1], acc[i][2], acc[i][3]);
}

// ---------------------------------------------------------------------------
// step_gemms<LVL>: flat-grid co-launch of the per-step GEMMs (768 blocks).
//  LVL 0: bid<512 -> h1 partials (m1@Wm, split-K2) ; else gm cols [0,1024)
//  LVL 1: bid<512 -> h2 partials (relu(hP0+hP1+bm)@Wm, split-K2)
//                    ; else gm cols [1024,2048)
//  gm: gates-m[b][s][:] = tm[b][s][:] @ Wmg[s], full-K, 64x64 tiles
// ---------------------------------------------------------------------------
template<int LVL>
__global__ __launch_bounds__(256)
void step_gemms(const float* __restrict__ m1, const float* __restrict__ Wm,
                const float* __restrict__ bm,
                float* __restrict__ hP, float* __restrict__ h2P,
                const float* __restrict__ tm, const float* __restrict__ Wmg,
                float* __restrict__ gm)
{
    __shared__ float As[32][68];
    __shared__ float Bs[32][68];
    const int bid = blockIdx.x;
    if (bid < 512) {
        int x = bid & 15, y = (bid >> 4) & 15, kc = bid >> 8;
        if (LVL == 0)
            gemm64_core<0>(m1, 1024, 0, nullptr, Wm, 1024,
                           hP + (long)kc * 1048576, 1024,
                           y * 64, x * 64, kc * 512, kc * 512 + 512, As, Bs);
        else
            gemm64_core<1>(hP, 1024, 1048576, bm, Wm, 1024,
                           h2P + (long)kc * 1048576, 1024,
                           y * 64, x * 64, kc * 512, kc * 512 + 512, As, Bs);
    } else {
        int j = bid - 512;
        int x = (j & 15) + (LVL == 0 ? 0 : 16);
        int y = (j >> 4) & 1, s = j >> 5;
        gemm64_core<0>(tm + s * 1024, 8192, 0, nullptr,
                       Wmg + (long)s * 2097152, 2048,
                       gm + s * 2048, 16384,
                       y * 64, x * 64, 0, 1024, As, Bs);
    }
}

// ---------------------------------------------------------------------------
// block reduction (256 threads) of (sum, sumsq); safe for repeated use
// ---------------------------------------------------------------------------
__device__ inline void block_reduce2(float& s1, float& s2)
{
    __shared__ float red[2][4];
    __syncthreads();
#pragma unroll
    for (int off = 32; off > 0; off >>= 1) {
        s1 += __shfl_down(s1, off, 64);
        s2 += __shfl_down(s2, off, 64);
    }
    int tid = threadIdx.x;
    if ((tid & 63) == 0) { red[0][tid >> 6] = s1; red[1][tid >> 6] = s2; }
    __syncthreads();
    s1 = red[0][0] + red[0][1] + red[0][2] + red[0][3];
    s2 = red[1][0] + red[1][1] + red[1][2] + red[1][3];
}

// ---------------------------------------------------------------------------
// ln1 (t=0): m1 = LN(mem0 + v[:,0])*g+b ; tm = tanh(mem0)
// ---------------------------------------------------------------------------
__global__ __launch_bounds__(256)
void ln1_kern(const float* __restrict__ memprev, const float* __restrict__ v,
              const float* __restrict__ g, const float* __restrict__ bb,
              float* __restrict__ m1, float* __restrict__ tm)
{
    const int row = blockIdx.x;
    const int b   = row >> 3;
    const int d   = threadIdx.x << 2;

    float4 mv = *(const float4*)(memprev + (long)row * DMEM + d);
    float4 vv = *(const float4*)(v + ((long)b * NT) * DMEM + d);

    *(float4*)(tm + (long)row * DMEM + d) =
        make_float4(tanhf(mv.x), tanhf(mv.y), tanhf(mv.z), tanhf(mv.w));

    float x0 = mv.x + vv.x, x1 = mv.y + vv.y, x2 = mv.z + vv.z, x3 = mv.w + vv.w;
    float s1 = x0 + x1 + x2 + x3;
    float s2 = x0 * x0 + x1 * x1 + x2 * x2 + x3 * x3;
    block_reduce2(s1, s2);
    float mean = s1 * (1.f / 1024.f);
    float var  = s2 * (1.f / 1024.f) - mean * mean;
    float inv  = 1.f / sqrtf(var + 1e-5f);

    float4 gg = *(const float4*)&g[d];
    float4 bv = *(const float4*)&bb[d];
    *(float4*)(m1 + (long)row * DMEM + d) =
        make_float4((x0 - mean) * inv * gg.x + bv.x,
                    (x1 - mean) * inv * gg.y + bv.y,
                    (x2 - mean) * inv * gg.z + bv.z,
                    (x3 - mean) * inv * gg.w + bv.w);
}

// ---------------------------------------------------------------------------
// fused tail: h2=relu(h2P0+h2P1+bm); t2=tanh(LN2(m1+h2));
// out = sig(gm+gi+ib)*t2 + sig(gm'+gi'+fb)*mem;
// if !last: tm=tanh(out); m1'=LN1(out+v[:,t+1])
// (m1in/m1out alias the same buffer; per-thread read-before-write is safe)
// ---------------------------------------------------------------------------
__global__ __launch_bounds__(256)
void step_fused(const float* m1in, const float* __restrict__ h2P,
                const float* __restrict__ bm,
                const float* __restrict__ g2, const float* __restrict__ b2,
                const float* __restrict__ gm, const float* __restrict__ gi, int t,
                const float* __restrict__ memprev,
                const float* __restrict__ fbp, const float* __restrict__ ibp,
                const float* __restrict__ v,
                const float* __restrict__ g1, const float* __restrict__ b1,
                float* __restrict__ outp, float* m1out,
                float* __restrict__ tm, int last)
{
    const int row = blockIdx.x;          // b*8+s
    const int b   = row >> 3;
    const int d   = threadIdx.x << 2;
    const long o  = (long)row * DMEM + d;

    // ---- ln2 ----
    float4 a  = *(const float4*)(m1in + o);
    float4 q0 = *(const float4*)(h2P + o);
    float4 q1 = *(const float4*)(h2P + 1048576 + o);
    float4 bb = *(const float4*)&bm[d];
    float x0 = a.x + fmaxf(q0.x + q1.x + bb.x, 0.f);
    float x1 = a.y + fmaxf(q0.y + q1.y + bb.y, 0.f);
    float x2 = a.z + fmaxf(q0.z + q1.z + bb.z, 0.f);
    float x3 = a.w + fmaxf(q0.w + q1.w + bb.w, 0.f);

    float s1 = x0 + x1 + x2 + x3;
    float s2 = x0 * x0 + x1 * x1 + x2 * x2 + x3 * x3;
    block_reduce2(s1, s2);
    float mean = s1 * (1.f / 1024.f);
    float var  = s2 * (1.f / 1024.f) - mean * mean;
    float inv  = 1.f / sqrtf(var + 1e-5f);

    float4 gg = *(const float4*)&g2[d];
    float4 b2v = *(const float4*)&b2[d];
    float t20 = tanhf((x0 - mean) * inv * gg.x + b2v.x);
    float t21 = tanhf((x1 - mean) * inv * gg.y + b2v.y);
    float t22 = tanhf((x2 - mean) * inv * gg.z + b2v.z);
    float t23 = tanhf((x3 - mean) * inv * gg.w + b2v.w);

    // ---- gates ----
    const float ib = *ibp, fb = *fbp;
    const long go = (long)row * NGATES + d;
    float4 ge0 = *(const float4*)(gm + go);
    float4 ge1 = *(const float4*)(gm + go + DMEM);
    const long io = ((long)b * NT + t) * NGATES + d;
    float4 i0 = *(const float4*)(gi + io);
    float4 i1 = *(const float4*)(gi + io + DMEM);
    float4 mv = *(const float4*)(memprev + o);

    float4 out;
    out.x = sigm(ge0.x + i0.x + ib) * t20 + sigm(ge1.x + i1.x + fb) * mv.x;
    out.y = sigm(ge0.y + i0.y + ib) * t21 + sigm(ge1.y + i1.y + fb) * mv.y;
    out.z = sigm(ge0.z + i0.z + ib) * t22 + sigm(ge1.z + i1.z + fb) * mv.z;
    out.w = sigm(ge0.w + i0.w + ib) * t23 + sigm(ge1.w + i1.w + fb) * mv.w;
    *(float4*)(outp + o) = out;

    // ---- next-step ln1 ----
    if (!last) {
        float4 vv = *(const float4*)(v + ((long)b * NT + t + 1) * DMEM + d);
        *(float4*)(tm + o) =
            make_float4(tanhf(out.x), tanhf(out.y), tanhf(out.z), tanhf(out.w));

        float y0 = out.x + vv.x, y1 = out.y + vv.y;
        float y2 = out.z + vv.z, y3 = out.w + vv.w;
        float u1 = y0 + y1 + y2 + y3;
        float u2 = y0 * y0 + y1 * y1 + y2 * y2 + y3 * y3;
        block_reduce2(u1, u2);
        float mean1 = u1 * (1.f / 1024.f);
        float var1  = u2 * (1.f / 1024.f) - mean1 * mean1;
        float inv1  = 1.f / sqrtf(var1 + 1e-5f);

        float4 g1v = *(const float4*)&g1[d];
        float4 b1v = *(const float4*)&b1[d];
        *(float4*)(m1out + o) =
            make_float4((y0 - mean1) * inv1 * g1v.x + b1v.x,
                        (y1 - mean1) * inv1 * g1v.y + b1v.y,
                        (y2 - mean1) * inv1 * g1v.z + b1v.z,
                        (y3 - mean1) * inv1 * g1v.w + b1v.w);
    }
}

// ---------------------------------------------------------------------------
extern "C" void kernel_launch(void* const* d_in, const int* in_sizes, int n_in,
                              void* d_out, int out_size, void* d_ws, size_t ws_size,
                              hipStream_t stream)
{
    const float* x    = (const float*)d_in[0];
    const float* mem0 = (const float*)d_in[1];
    const float* Wi   = (const float*)d_in[2];
    const float* bi   = (const float*)d_in[3];
    // d_in[4..7] = Wq,bq,Wk,bk : dead (softmax over singleton axis == 1)
    const float* Wv   = (const float*)d_in[8];
    const float* bv   = (const float*)d_in[9];
    const float* Wm   = (const float*)d_in[10];
    const float* bm   = (const float*)d_in[11];
    const float* ln1g = (const float*)d_in[12];
    const float* ln1b = (const float*)d_in[13];
    const float* ln2g = (const float*)d_in[14];
    const float* ln2b = (const float*)d_in[15];
    const float* repw = (const float*)d_in[16];
    const float* Wg   = (const float*)d_in[17];
    const float* bg   = (const float*)d_in[18];
    const float* Wmg  = (const float*)d_in[19];
    const float* fbp  = (const float*)d_in[20];
    const float* ibp  = (const float*)d_in[21];

    float* out = (float*)d_out;
    char*  ws  = (char*)d_ws;
    const long MB = 1024L * 1024L;

    // persistent across scan
    float* v    = (float*)(ws + 0 * MB);   // 16 MB [4096][1024]
    float* gi   = (float*)(ws + 16 * MB);  // 32 MB [4096][2048]
    // per-step
    float* m1   = (float*)(ws + 48 * MB);  //  4 MB
    float* tm   = (float*)(ws + 52 * MB);  //  4 MB
    float* hP   = (float*)(ws + 56 * MB);  //  8 MB [2][1024][1024] h1 partials
    float* gm   = (float*)(ws + 64 * MB);  //  8 MB [128][8][2048]
    float* h2P  = (float*)(ws + 72 * MB);  //  8 MB [2][1024][1024] h2 partials
    // phase-A transient (dead before ln1 writes m1)
    float* inp  = (float*)(ws + 48 * MB);  // 16 MB [4096][1024]
    // peak exactly 80 MB (proven available)

    dim3 blk(256);

    // ---- phase A ----
    // inp = x @ Wi + bi
    gemm128<0><<<dim3(8, 32, 1), blk, 0, stream>>>(x, 1024, nullptr,
                                                   Wi, 1024, bi, inp, 1024);
    // v = inp @ Wv + bv
    gemm128<0><<<dim3(8, 32, 1), blk, 0, stream>>>(inp, 1024, nullptr,
                                                   Wv, 1024, bv, v, 1024);
    // gi = relu(rep_w * inp) @ Wg + bg   (ga fused into A-staging)
    gemm128<2><<<dim3(16, 32, 1), blk, 0, stream>>>(inp, 1024, repw,
                                                    Wg, 2048, bg, gi, 1024);

    // ---- t=0 LN1 + tanh(mem0) ----
    ln1_kern<<<1024, blk, 0, stream>>>(mem0, v, ln1g, ln1b, m1, tm);

    // ---- recurrent scan; state lives in d_out (outs[t] == new_mem_t) ----
    const long stepN = (long)NB * 8 * DMEM;   // 1,048,576 floats
    for (int t = 0; t < NT; ++t) {
        const float* memprev = (t == 0) ? mem0 : out + (long)(t - 1) * stepN;

        // level 1: h1 partials (split-K2) || gm columns [0,1024)
        step_gemms<0><<<768, blk, 0, stream>>>(m1, Wm, bm, hP, h2P, tm, Wmg, gm);
        // level 2: h2 partials (fold hP, split-K2) || gm columns [1024,2048)
        step_gemms<1><<<768, blk, 0, stream>>>(m1, Wm, bm, hP, h2P, tm, Wmg, gm);
        // fused: ln2 + gates + state update + next ln1
        step_fused<<<1024, blk, 0, stream>>>(
            m1, h2P, bm, ln2g, ln2b, gm, gi, t, memprev, fbp, ibp,
            v, ln1g, ln1b, out + (long)t * stepN, m1, tm,
            (t == NT - 1) ? 1 : 0);
    }

    // final_mem = outs[31]
    hipMemcpyAsync(out + 32L * stepN, out + 31L * stepN, stepN * sizeof(float),
                   hipMemcpyDeviceToDevice, stream);
}